// Round 7
// baseline (213.240 us; speedup 1.0000x reference)
//
#include <hip/hip_runtime.h>
#include <hip/hip_bf16.h>

constexpr int IN_CH  = 128;
constexpr int HID_CH = 128;
constexpr int OUT_CH = 64;
constexpr int SCAN_CHUNK = 1024;   // elements per scan block (256 thr x 4)

typedef __attribute__((ext_vector_type(8))) short bf16x8;
typedef __attribute__((ext_vector_type(4))) float f32x4;

// ---------------- bf16 pack/unpack helpers ----------------

__device__ inline unsigned short f2bf(float f) {
  __hip_bfloat16 h = __float2bfloat16(f);   // RN
  return *reinterpret_cast<unsigned short*>(&h);
}
__device__ inline unsigned pack_bf16x2(float lo, float hi) {
  return (unsigned)f2bf(lo) | ((unsigned)f2bf(hi) << 16);
}
__device__ inline float bf_lo(unsigned u) { return __uint_as_float(u << 16); }
__device__ inline float bf_hi(unsigned u) { return __uint_as_float(u & 0xffff0000u); }

// ---------------- workspace/output zeroing ----------------
// cnt must be zero every call; d_out must be zeroed because decode accumulates
// two pass-partials via atomicAdd (harness poisons d_out before timing).

__global__ __launch_bounds__(256) void k_zero(int* __restrict__ a, int na,
                                              float* __restrict__ b, int nb) {
  int i = (blockIdx.x * 256 + threadIdx.x) * 4;
  if (i + 3 < na) *(int4*)&a[i] = make_int4(0, 0, 0, 0);
  else for (int j = 0; j < 4 && i + j < na; ++j) a[i + j] = 0;
  if (i + 3 < nb) *(float4*)&b[i] = make_float4(0.f, 0.f, 0.f, 0.f);
  else for (int j = 0; j < 4 && i + j < nb; ++j) b[i + j] = 0.f;
}

// ---------------- CSR build ----------------
// count degree AND remember each edge's slot (ord) so k_fill needs no atomics.

__global__ void k_count(const int* __restrict__ dst, int* __restrict__ cnt,
                        int* __restrict__ ord, int E) {
  int e = (blockIdx.x * blockDim.x + threadIdx.x) * 4;
  if (e + 3 < E) {
    int4 v = *(const int4*)&dst[e];
    int4 o;
    o.x = atomicAdd(&cnt[v.x], 1);
    o.y = atomicAdd(&cnt[v.y], 1);
    o.z = atomicAdd(&cnt[v.z], 1);
    o.w = atomicAdd(&cnt[v.w], 1);
    *(int4*)&ord[e] = o;
  } else {
    for (int j = 0; j < 4 && e + j < E; ++j) ord[e + j] = atomicAdd(&cnt[dst[e + j]], 1);
  }
}

// phase 1 of scan, fused with dinv computation (both only read cnt)
__global__ __launch_bounds__(256) void k_scan_part(const int* __restrict__ cnt,
                                                   int* __restrict__ bsum,
                                                   float* __restrict__ dinv, int N) {
  int t = threadIdx.x;
  int base = blockIdx.x * SCAN_CHUNK + t * 4;
  int s = 0;
  if (base + 3 < N) {
    int4 v = *(const int4*)&cnt[base];
    s = v.x + v.y + v.z + v.w;
    float4 d;
    d.x = rsqrtf((float)v.x + 1.0f);
    d.y = rsqrtf((float)v.y + 1.0f);
    d.z = rsqrtf((float)v.z + 1.0f);
    d.w = rsqrtf((float)v.w + 1.0f);
    *(float4*)&dinv[base] = d;
  } else {
    for (int j = 0; j < 4; ++j)
      if (base + j < N) {
        int c = cnt[base + j];
        s += c;
        dinv[base + j] = rsqrtf((float)c + 1.0f);
      }
  }
  __shared__ int red[256];
  red[t] = s; __syncthreads();
  for (int off = 128; off; off >>= 1) {
    if (t < off) red[t] += red[t + off];
    __syncthreads();
  }
  if (t == 0) bsum[blockIdx.x] = red[0];
}

// phase 2+3 fused: each block derives its global offset from bsum (nblk <= 64)
__global__ __launch_bounds__(256) void k_scan_fill(const int* __restrict__ cnt,
                                                   const int* __restrict__ bsum,
                                                   int* __restrict__ rowptr, int N, int E) {
  int t = threadIdx.x;
  int boff = 0;
  for (int i = 0; i < blockIdx.x; ++i) boff += bsum[i];  // tiny: <64 scalar loads
  int base = blockIdx.x * SCAN_CHUNK + t * 4;
  int v[4] = {0, 0, 0, 0};
  if (base + 3 < N) {
    int4 q = *(const int4*)&cnt[base];
    v[0] = q.x; v[1] = q.y; v[2] = q.z; v[3] = q.w;
  } else {
    for (int j = 0; j < 4; ++j) if (base + j < N) v[j] = cnt[base + j];
  }
  int mysum = v[0] + v[1] + v[2] + v[3];
  __shared__ int s[256];
  s[t] = mysum; __syncthreads();
  for (int off = 1; off < 256; off <<= 1) {
    int add = (t >= off) ? s[t - off] : 0;
    __syncthreads();
    s[t] += add;
    __syncthreads();
  }
  int run = boff + s[t] - mysum;  // exclusive prefix for my 4
  for (int j = 0; j < 4; ++j) {
    if (base + j < N) rowptr[base + j] = run;
    run += v[j];
  }
  if (blockIdx.x == 0 && t == 0) rowptr[N] = E;
}

__global__ void k_fill(const int* __restrict__ src, const int* __restrict__ dst,
                       const int* __restrict__ ord, const int* __restrict__ rowptr,
                       int* __restrict__ col, int E) {
  int e0 = (blockIdx.x * blockDim.x + threadIdx.x) * 4;
  if (e0 >= E) return;
  if (e0 + 3 < E) {
    int4 sv = *(const int4*)&src[e0];
    int4 dv = *(const int4*)&dst[e0];
    int4 ov = *(const int4*)&ord[e0];
    col[rowptr[dv.x] + ov.x] = sv.x;
    col[rowptr[dv.y] + ov.y] = sv.y;
    col[rowptr[dv.z] + ov.z] = sv.z;
    col[rowptr[dv.w] + ov.w] = sv.w;
  } else {
    for (int j = 0; j < 4 && e0 + j < E; ++j)
      col[rowptr[dst[e0 + j]] + ord[e0 + j]] = src[e0 + j];
  }
}

// ---------------- MFMA bf16 GEMM, pass-major bf16 output ----------------
// Yp[pass][r][c32] = bf16( (X[r,:] @ W[:,pass*32+c32]) * dinv[r] ),  K = 128.
// Pass-major output = 32-channel slices, so each gather-pass table slice is
// 2.5 MB and fits one XCD's 4 MB L2 (see k_agg).
// 256 thr = 4 waves; wave w owns rows [blk*64 + 16w, +16), all OUT cols.
// W staged once to LDS as Wt[col][k] bf16, T2 XOR swizzle (byte ^= (col&7)<<4).
// MFMA 16x16x32 lane map: A: row=l&15, k=(l>>4)*8+j ; B: col=l&15, same k;
// C/D: col=l&15, row=(l>>4)*4+reg  [m89].
// A_BF16: A itself is a pass-major bf16 table [KD/32][N][32] (layer-2 input).

template <int OUT, bool A_BF16>
__global__ __launch_bounds__(256) void k_gemm(const void* __restrict__ Xv,
                                              const float* __restrict__ W,
                                              const float* __restrict__ dinv,
                                              unsigned short* __restrict__ Y, int N) {
  constexpr int KD = 128;
  __shared__ unsigned short Wt[OUT * KD];  // [col][k] bf16, XOR-swizzled
  int t = threadIdx.x;
  for (int i = t * 4; i < KD * OUT; i += 1024) {
    int k = i / OUT, c = i % OUT;
    float4 w4 = *(const float4*)&W[i];
    float wa[4] = {w4.x, w4.y, w4.z, w4.w};
#pragma unroll
    for (int j = 0; j < 4; ++j) {
      int colj = c + j;
      int byte = colj * (KD * 2) + k * 2;
      byte ^= ((colj & 7) << 4);
      *(unsigned short*)((char*)Wt + byte) = f2bf(wa[j]);
    }
  }
  __syncthreads();

  int w = t >> 6, l = t & 63;
  int lr = l & 15, kg = (l >> 4) * 8;
  int r = blockIdx.x * 64 + w * 16 + lr;
  bool valid = r < N;

  f32x4 acc[OUT / 16];
#pragma unroll
  for (int n = 0; n < OUT / 16; ++n) acc[n] = f32x4{0.f, 0.f, 0.f, 0.f};

#pragma unroll
  for (int kb = 0; kb < KD / 32; ++kb) {
    bf16x8 a = bf16x8{0, 0, 0, 0, 0, 0, 0, 0};
    if (valid) {
      if (A_BF16) {
        // pass-major: channels kb*32+kg..+8 live in pass kb at offset kg
        a = *(const bf16x8*)((const unsigned short*)Xv + ((size_t)kb * N + r) * 32 + kg);
      } else {
        const float* xrow = (const float*)Xv + (size_t)r * KD + kb * 32 + kg;
        float4 x0 = *(const float4*)xrow;
        float4 x1 = *(const float4*)(xrow + 4);
        a[0] = (short)f2bf(x0.x); a[1] = (short)f2bf(x0.y);
        a[2] = (short)f2bf(x0.z); a[3] = (short)f2bf(x0.w);
        a[4] = (short)f2bf(x1.x); a[5] = (short)f2bf(x1.y);
        a[6] = (short)f2bf(x1.z); a[7] = (short)f2bf(x1.w);
      }
    }
#pragma unroll
    for (int n = 0; n < OUT / 16; ++n) {
      int col = n * 16 + lr;
      int byte = col * (KD * 2) + (kb * 32 + kg) * 2;
      byte ^= ((col & 7) << 4);
      bf16x8 b = *(const bf16x8*)((const char*)Wt + byte);
      acc[n] = __builtin_amdgcn_mfma_f32_16x16x32_bf16(a, b, acc[n], 0, 0, 0);
    }
  }

  // epilogue: scale rows by dinv, pack bf16, pass-major write.
  int orow = blockIdx.x * 64 + w * 16 + (l >> 4) * 4;
  float dn[4];
#pragma unroll
  for (int i = 0; i < 4; ++i) dn[i] = (orow + i < N) ? dinv[orow + i] : 0.f;
#pragma unroll
  for (int i = 0; i < 4; ++i) {
    if (orow + i >= N) continue;
#pragma unroll
    for (int n = 0; n < OUT / 16; ++n)
      Y[((size_t)(n >> 1) * N + (orow + i)) * 32 + (n & 1) * 16 + lr] =
          f2bf(acc[n][i] * dn[i]);
  }
}

// ---------------- pass-split, XCD-pinned aggregation ----------------
// T = bf16 table, pass-major uint view [NPASS][N][16]; each pass slice is
// N*64 B = 2.5 MB -> fits one XCD's 4 MB L2. Pass pinned to XCDs via
// blockIdx%8 (performance heuristic only; correct under any mapping).
// Block = 4 waves, wave = one node: 16-lane groups gather 4 edges at a time
// (64 B per edge), 4-deep unroll = 16 edges in flight per wave.
// Out[pass][n][cp] = pack( act(dn*(self + sum_nbr) + bias) ).

template <int NPASS, bool RELU>
__global__ __launch_bounds__(256) void k_agg(const unsigned* __restrict__ T,
                                             const int* __restrict__ rowptr,
                                             const int* __restrict__ col,
                                             const float* __restrict__ dinv,
                                             const float* __restrict__ bias,
                                             unsigned* __restrict__ Out, int N) {
  constexpr int SUBS = 8 / NPASS;          // XCDs per pass
  int bid = blockIdx.x;
  int xcd = bid & 7, chunk = bid >> 3;
  int pass = xcd / SUBS, sub = xcd % SUBS;
  int w = threadIdx.x >> 6, l = threadIdx.x & 63;
  int n = (chunk * SUBS + sub) * 4 + w;
  if (n >= N) return;
  int grp = l >> 4, cp = l & 15;
  const unsigned* Tp = T + (size_t)pass * N * 16;
  float dn = dinv[n];
  float ax = 0.f, ay = 0.f;
  if (grp == 0) {                           // self-loop term, counted once
    unsigned u0 = Tp[(size_t)n * 16 + cp];
    ax = bf_lo(u0); ay = bf_hi(u0);
  }
  int pend = rowptr[n + 1];
  int e = rowptr[n] + grp;
  for (; e + 12 < pend; e += 16) {          // 4 gathers in flight (16 edges/wave)
    int c0 = __builtin_nontemporal_load(&col[e]);
    int c1 = __builtin_nontemporal_load(&col[e + 4]);
    int c2 = __builtin_nontemporal_load(&col[e + 8]);
    int c3 = __builtin_nontemporal_load(&col[e + 12]);
    unsigned u0 = Tp[(size_t)c0 * 16 + cp];
    unsigned u1 = Tp[(size_t)c1 * 16 + cp];
    unsigned u2 = Tp[(size_t)c2 * 16 + cp];
    unsigned u3 = Tp[(size_t)c3 * 16 + cp];
    ax += bf_lo(u0) + bf_lo(u1) + bf_lo(u2) + bf_lo(u3);
    ay += bf_hi(u0) + bf_hi(u1) + bf_hi(u2) + bf_hi(u3);
  }
  for (; e < pend; e += 4) {
    int c = __builtin_nontemporal_load(&col[e]);
    unsigned u = Tp[(size_t)c * 16 + cp];
    ax += bf_lo(u); ay += bf_hi(u);
  }
  ax += __shfl_xor(ax, 16); ax += __shfl_xor(ax, 32);
  ay += __shfl_xor(ay, 16); ay += __shfl_xor(ay, 32);
  if (grp == 0) {
    float2 b2 = ((const float2*)(bias + pass * 32))[cp];
    float vx = dn * ax + b2.x, vy = dn * ay + b2.y;
    if (RELU) { vx = fmaxf(vx, 0.f); vy = fmaxf(vy, 0.f); }
    Out[(size_t)pass * N * 16 + (size_t)n * 16 + cp] = pack_bf16x2(vx, vy);
  }
}

// ---------------- decode: logits[i] = dot(z[a[i]], z[b[i]]), pass-split ----------------
// 2 passes x 4 XCDs; 16 lanes per pair per pass (64 B gathers into L2-resident
// 2.5 MB slice). Partial dots accumulate via fp32 atomicAdd (2 commutative
// adds per address -> deterministic). out must be pre-zeroed (k_zero).

__global__ __launch_bounds__(256) void k_decode(const unsigned* __restrict__ Z,
                                                const int* __restrict__ ia,
                                                const int* __restrict__ ib,
                                                float* __restrict__ out, int N, int L) {
  int bid = blockIdx.x;
  int xcd = bid & 7, chunk = bid >> 3;
  int pass = xcd >> 2, sub = xcd & 3;
  int t = threadIdx.x;
  int i = (chunk * 4 + sub) * 16 + (t >> 4);
  if (i >= L) return;
  int e = t & 15;
  int a = ia[i], b = ib[i];
  const unsigned* Zp = Z + (size_t)pass * N * 16;
  unsigned za = Zp[(size_t)a * 16 + e];
  unsigned zb = Zp[(size_t)b * 16 + e];
  float p = bf_lo(za) * bf_lo(zb) + bf_hi(za) * bf_hi(zb);
  p += __shfl_xor(p, 1);
  p += __shfl_xor(p, 2);
  p += __shfl_xor(p, 4);
  p += __shfl_xor(p, 8);
  if (e == 0) atomicAdd(&out[i], p);
}

extern "C" void kernel_launch(void* const* d_in, const int* in_sizes, int n_in,
                              void* d_out, int out_size, void* d_ws, size_t ws_size,
                              hipStream_t stream) {
  const float* x   = (const float*)d_in[0];
  const int*   ei  = (const int*)d_in[1];
  const int*   eli = (const int*)d_in[2];
  const float* W1  = (const float*)d_in[3];
  const float* b1  = (const float*)d_in[4];
  const float* W2  = (const float*)d_in[5];
  const float* b2  = (const float*)d_in[6];
  float* logits = (float*)d_out;

  int N = in_sizes[0] / IN_CH;
  int E = in_sizes[1] / 2;
  int L = in_sizes[2] / 2;
  const int* src = ei;
  const int* dst = ei + E;
  const int* la  = eli;
  const int* lb  = eli + L;

  char* ws = (char*)d_ws;
  size_t off = 0;
  auto alloc = [&](size_t bytes) {
    void* p = ws + off;
    off = (off + bytes + 255) & ~(size_t)255;
    return p;
  };
  int*      cnt    = (int*)alloc((size_t)N * 4);
  int*      rowptr = (int*)alloc((size_t)(N + 1) * 4);
  float*    dinv   = (float*)alloc((size_t)N * 4);
  int*      col    = (int*)alloc((size_t)E * 4);
  int*      ord    = (int*)alloc((size_t)E * 4);
  unsigned short* hsp  = (unsigned short*)alloc((size_t)N * HID_CH * 2);  // [4][N][32] bf16
  unsigned short* hrbp = (unsigned short*)alloc((size_t)N * HID_CH * 2);  // [4][N][32] bf16
  unsigned short* h2sp = (unsigned short*)alloc((size_t)N * OUT_CH * 2);  // [2][N][32] bf16
  unsigned short* zup  = (unsigned short*)alloc((size_t)N * OUT_CH * 2);  // [2][N][32] bf16
  int*      bsum   = (int*)alloc(256 * 4);

  const int TB = 256;
  int nscan = (N + SCAN_CHUNK - 1) / SCAN_CHUNK;
  int nzero = max(N, L);
  // cnt and out must be zero EVERY call (decode atomically accumulates into out)
  k_zero<<<(nzero / 4 + TB - 1) / TB, TB, 0, stream>>>(cnt, N, logits, L);
  k_count<<<(E / 4 + TB - 1) / TB, TB, 0, stream>>>(dst, cnt, ord, E);
  k_scan_part<<<nscan, 256, 0, stream>>>(cnt, bsum, dinv, N);
  k_scan_fill<<<nscan, 256, 0, stream>>>(cnt, bsum, rowptr, N, E);
  k_fill <<<(E / 4 + TB - 1) / TB, TB, 0, stream>>>(src, dst, ord, rowptr, col, E);

  // layer 1: hsp = bf16((x@W1)*dinv) ; hrbp = bf16(relu(dn*(self+sum) + b1))
  k_gemm<HID_CH, false><<<(N + 63) / 64, 256, 0, stream>>>(x, W1, dinv, hsp, N);
  k_agg<4, true><<<((N + 7) / 8) * 8, 256, 0, stream>>>(
      (const unsigned*)hsp, rowptr, col, dinv, b1, (unsigned*)hrbp, N);

  // layer 2: h2sp = bf16((hrbp@W2)*dinv) ; zup = bf16(dn*(self+sum) + b2)
  k_gemm<OUT_CH, true><<<(N + 63) / 64, 256, 0, stream>>>(hrbp, W2, dinv, h2sp, N);
  k_agg<2, false><<<((N + 15) / 16) * 8, 256, 0, stream>>>(
      (const unsigned*)h2sp, rowptr, col, dinv, b2, (unsigned*)zup, N);

  // decode (2 pass-partials accumulated atomically)
  k_decode<<<((L + 63) / 64) * 8, 256, 0, stream>>>(
      (const unsigned*)zup, la, lb, logits, N, L);
}

// Round 8
// 144.365 us; speedup vs baseline: 1.4771x; 1.4771x over previous
//
#include <hip/hip_runtime.h>
#include <hip/hip_bf16.h>

constexpr int IN_CH  = 128;
constexpr int HID_CH = 128;
constexpr int OUT_CH = 64;
constexpr int SCAN_CHUNK = 1024;   // elements per scan block (256 thr x 4)

typedef __attribute__((ext_vector_type(8))) short bf16x8;
typedef __attribute__((ext_vector_type(4))) float f32x4;

// ---------------- bf16 pack/unpack helpers ----------------

__device__ inline unsigned short f2bf(float f) {
  __hip_bfloat16 h = __float2bfloat16(f);   // RN
  return *reinterpret_cast<unsigned short*>(&h);
}
__device__ inline unsigned pack_bf16x2(float lo, float hi) {
  return (unsigned)f2bf(lo) | ((unsigned)f2bf(hi) << 16);
}
__device__ inline float bf_lo(unsigned u) { return __uint_as_float(u << 16); }
__device__ inline float bf_hi(unsigned u) { return __uint_as_float(u & 0xffff0000u); }

// ---------------- workspace zeroing ----------------

__global__ __launch_bounds__(256) void k_zero(int* __restrict__ a, int n) {
  int i = (blockIdx.x * 256 + threadIdx.x) * 4;
  if (i + 3 < n) *(int4*)&a[i] = make_int4(0, 0, 0, 0);
  else for (int j = 0; j < 4 && i + j < n; ++j) a[i + j] = 0;
}

// ---------------- CSR build ----------------
// count degree AND remember each edge's slot (ord) so k_fill needs no atomics.

__global__ void k_count(const int* __restrict__ dst, int* __restrict__ cnt,
                        int* __restrict__ ord, int E) {
  int e = (blockIdx.x * blockDim.x + threadIdx.x) * 4;
  if (e + 3 < E) {
    int4 v = *(const int4*)&dst[e];
    int4 o;
    o.x = atomicAdd(&cnt[v.x], 1);
    o.y = atomicAdd(&cnt[v.y], 1);
    o.z = atomicAdd(&cnt[v.z], 1);
    o.w = atomicAdd(&cnt[v.w], 1);
    *(int4*)&ord[e] = o;
  } else {
    for (int j = 0; j < 4 && e + j < E; ++j) ord[e + j] = atomicAdd(&cnt[dst[e + j]], 1);
  }
}

// phase 1 of scan, fused with dinv computation (both only read cnt)
__global__ __launch_bounds__(256) void k_scan_part(const int* __restrict__ cnt,
                                                   int* __restrict__ bsum,
                                                   float* __restrict__ dinv, int N) {
  int t = threadIdx.x;
  int base = blockIdx.x * SCAN_CHUNK + t * 4;
  int s = 0;
  if (base + 3 < N) {
    int4 v = *(const int4*)&cnt[base];
    s = v.x + v.y + v.z + v.w;
    float4 d;
    d.x = rsqrtf((float)v.x + 1.0f);
    d.y = rsqrtf((float)v.y + 1.0f);
    d.z = rsqrtf((float)v.z + 1.0f);
    d.w = rsqrtf((float)v.w + 1.0f);
    *(float4*)&dinv[base] = d;
  } else {
    for (int j = 0; j < 4; ++j)
      if (base + j < N) {
        int c = cnt[base + j];
        s += c;
        dinv[base + j] = rsqrtf((float)c + 1.0f);
      }
  }
  __shared__ int red[256];
  red[t] = s; __syncthreads();
  for (int off = 128; off; off >>= 1) {
    if (t < off) red[t] += red[t + off];
    __syncthreads();
  }
  if (t == 0) bsum[blockIdx.x] = red[0];
}

// phase 2+3 fused: each block derives its global offset from bsum (nblk <= 64)
__global__ __launch_bounds__(256) void k_scan_fill(const int* __restrict__ cnt,
                                                   const int* __restrict__ bsum,
                                                   int* __restrict__ rowptr, int N, int E) {
  int t = threadIdx.x;
  int boff = 0;
  for (int i = 0; i < blockIdx.x; ++i) boff += bsum[i];  // tiny: <64 scalar loads
  int base = blockIdx.x * SCAN_CHUNK + t * 4;
  int v[4] = {0, 0, 0, 0};
  if (base + 3 < N) {
    int4 q = *(const int4*)&cnt[base];
    v[0] = q.x; v[1] = q.y; v[2] = q.z; v[3] = q.w;
  } else {
    for (int j = 0; j < 4; ++j) if (base + j < N) v[j] = cnt[base + j];
  }
  int mysum = v[0] + v[1] + v[2] + v[3];
  __shared__ int s[256];
  s[t] = mysum; __syncthreads();
  for (int off = 1; off < 256; off <<= 1) {
    int add = (t >= off) ? s[t - off] : 0;
    __syncthreads();
    s[t] += add;
    __syncthreads();
  }
  int run = boff + s[t] - mysum;  // exclusive prefix for my 4
  for (int j = 0; j < 4; ++j) {
    if (base + j < N) rowptr[base + j] = run;
    run += v[j];
  }
  if (blockIdx.x == 0 && t == 0) rowptr[N] = E;
}

__global__ void k_fill(const int* __restrict__ src, const int* __restrict__ dst,
                       const int* __restrict__ ord, const int* __restrict__ rowptr,
                       int* __restrict__ col, int E) {
  int e0 = (blockIdx.x * blockDim.x + threadIdx.x) * 4;
  if (e0 >= E) return;
  if (e0 + 3 < E) {
    int4 sv = *(const int4*)&src[e0];
    int4 dv = *(const int4*)&dst[e0];
    int4 ov = *(const int4*)&ord[e0];
    col[rowptr[dv.x] + ov.x] = sv.x;
    col[rowptr[dv.y] + ov.y] = sv.y;
    col[rowptr[dv.z] + ov.z] = sv.z;
    col[rowptr[dv.w] + ov.w] = sv.w;
  } else {
    for (int j = 0; j < 4 && e0 + j < E; ++j)
      col[rowptr[dst[e0 + j]] + ord[e0 + j]] = src[e0 + j];
  }
}

// ---------------- MFMA bf16 GEMM, 2-pass-major bf16 output ----------------
// Y[pass][r][c'] = bf16( (X[r,:] @ W[:,pass*(OUT/2)+c']) * dinv[r] ), K = 128.
// Pass-major output (2 slices of OUT/2 channels) so each aggregation pass
// gathers from a slice that (mostly) fits one XCD's 4 MB L2.
// 256 thr = 4 waves; wave w owns rows [blk*64 + 16w, +16), all OUT cols.
// W staged to LDS as Wt[col][k] bf16, T2 XOR swizzle (byte ^= (col&7)<<4).
// MFMA 16x16x32 lane map: A: row=l&15, k=(l>>4)*8+j ; B: col=l&15, same k;
// C/D: col=l&15, row=(l>>4)*4+reg  [m89].
// A_BF16: A is the pass-major bf16 table [2][N][64] from the previous layer.

template <int OUT, bool A_BF16>
__global__ __launch_bounds__(256) void k_gemm(const void* __restrict__ Xv,
                                              const float* __restrict__ W,
                                              const float* __restrict__ dinv,
                                              unsigned short* __restrict__ Y, int N) {
  constexpr int KD = 128;
  constexpr int NCG = OUT / 32;            // 16-col groups per pass
  __shared__ unsigned short Wt[OUT * KD];  // [col][k] bf16, XOR-swizzled
  int t = threadIdx.x;
  for (int i = t * 4; i < KD * OUT; i += 1024) {
    int k = i / OUT, c = i % OUT;
    float4 w4 = *(const float4*)&W[i];
    float wa[4] = {w4.x, w4.y, w4.z, w4.w};
#pragma unroll
    for (int j = 0; j < 4; ++j) {
      int colj = c + j;
      int byte = colj * (KD * 2) + k * 2;
      byte ^= ((colj & 7) << 4);
      *(unsigned short*)((char*)Wt + byte) = f2bf(wa[j]);
    }
  }
  __syncthreads();

  int w = t >> 6, l = t & 63;
  int lr = l & 15, kg = (l >> 4) * 8;
  int r = blockIdx.x * 64 + w * 16 + lr;
  bool valid = r < N;

  f32x4 acc[OUT / 16];
#pragma unroll
  for (int n = 0; n < OUT / 16; ++n) acc[n] = f32x4{0.f, 0.f, 0.f, 0.f};

#pragma unroll
  for (int kb = 0; kb < KD / 32; ++kb) {
    bf16x8 a = bf16x8{0, 0, 0, 0, 0, 0, 0, 0};
    if (valid) {
      if (A_BF16) {
        // input table is [2][N][64]: pass kb>>1, channel (kb&1)*32 + kg
        a = *(const bf16x8*)((const unsigned short*)Xv +
                             ((size_t)(kb >> 1) * N + r) * 64 + (kb & 1) * 32 + kg);
      } else {
        const float* xrow = (const float*)Xv + (size_t)r * KD + kb * 32 + kg;
        float4 x0 = *(const float4*)xrow;
        float4 x1 = *(const float4*)(xrow + 4);
        a[0] = (short)f2bf(x0.x); a[1] = (short)f2bf(x0.y);
        a[2] = (short)f2bf(x0.z); a[3] = (short)f2bf(x0.w);
        a[4] = (short)f2bf(x1.x); a[5] = (short)f2bf(x1.y);
        a[6] = (short)f2bf(x1.z); a[7] = (short)f2bf(x1.w);
      }
    }
#pragma unroll
    for (int n = 0; n < OUT / 16; ++n) {
      int col = n * 16 + lr;
      int byte = col * (KD * 2) + (kb * 32 + kg) * 2;
      byte ^= ((col & 7) << 4);
      bf16x8 b = *(const bf16x8*)((const char*)Wt + byte);
      acc[n] = __builtin_amdgcn_mfma_f32_16x16x32_bf16(a, b, acc[n], 0, 0, 0);
    }
  }

  // epilogue: scale rows by dinv, pack bf16, pass-major [2][N][OUT/2] write.
  int orow = blockIdx.x * 64 + w * 16 + (l >> 4) * 4;
  float dn[4];
#pragma unroll
  for (int i = 0; i < 4; ++i) dn[i] = (orow + i < N) ? dinv[orow + i] : 0.f;
#pragma unroll
  for (int i = 0; i < 4; ++i) {
    if (orow + i >= N) continue;
#pragma unroll
    for (int n = 0; n < OUT / 16; ++n)
      Y[((size_t)(n / NCG) * N + (orow + i)) * (OUT / 2) + (n % NCG) * 16 + lr] =
          f2bf(acc[n][i] * dn[i]);
  }
}

// ---------------- 2-pass XCD-pinned aggregation, node-parallel lanes ----------------
// T = pass-major uint view [2][N][CPU] (CPU uints = 2*CPU channels per pass).
// Pass pinned to an XCD group via blockIdx&7 (perf heuristic; correct under
// any mapping). Wave = 64/CPU node-passes side by side: each lane owns one
// channel-pair of one node for the whole edge loop -> same wave count as the
// unsplit kernel (R7 lesson), no reduce, no atomics. Edges walked serially
// per node, 8/4/1-deep gather pipeline; col loads nontemporal.

template <int CPU, bool RELU>
__global__ __launch_bounds__(256) void k_agg(const unsigned* __restrict__ T,
                                             const int* __restrict__ rowptr,
                                             const int* __restrict__ col,
                                             const float* __restrict__ dinv,
                                             const float* __restrict__ bias,
                                             unsigned* __restrict__ Out, int N) {
  constexpr int NPW = 64 / CPU;   // node-passes per wave
  constexpr int NPB = 4 * NPW;    // nodes per block (per its pass)
  int bid = blockIdx.x;
  int xcd = bid & 7, chunk = bid >> 3;
  int pass = xcd >> 2, sub = xcd & 3;
  int w = threadIdx.x >> 6, l = threadIdx.x & 63;
  int n = (chunk * 4 + sub) * NPB + w * NPW + l / CPU;
  if (n >= N) return;
  int cp = l % CPU;
  const unsigned* Tp = T + (size_t)pass * N * CPU;
  float dn = dinv[n];
  unsigned u0 = Tp[(size_t)n * CPU + cp];      // self-loop term
  float ax = bf_lo(u0), ay = bf_hi(u0);
  int p = rowptr[n], pend = rowptr[n + 1];
  for (; p + 8 <= pend; p += 8) {
    int s[8]; unsigned g[8];
#pragma unroll
    for (int j = 0; j < 8; ++j) s[j] = __builtin_nontemporal_load(&col[p + j]);
#pragma unroll
    for (int j = 0; j < 8; ++j) g[j] = Tp[(size_t)s[j] * CPU + cp];
#pragma unroll
    for (int j = 0; j < 8; ++j) { ax += bf_lo(g[j]); ay += bf_hi(g[j]); }
  }
  if (p + 4 <= pend) {
    int s[4]; unsigned g[4];
#pragma unroll
    for (int j = 0; j < 4; ++j) s[j] = __builtin_nontemporal_load(&col[p + j]);
#pragma unroll
    for (int j = 0; j < 4; ++j) g[j] = Tp[(size_t)s[j] * CPU + cp];
#pragma unroll
    for (int j = 0; j < 4; ++j) { ax += bf_lo(g[j]); ay += bf_hi(g[j]); }
    p += 4;
  }
  for (; p < pend; ++p) {
    unsigned g = Tp[(size_t)__builtin_nontemporal_load(&col[p]) * CPU + cp];
    ax += bf_lo(g); ay += bf_hi(g);
  }
  float2 b2 = ((const float2*)bias)[pass * CPU + cp];
  float vx = dn * ax + b2.x, vy = dn * ay + b2.y;
  if (RELU) { vx = fmaxf(vx, 0.f); vy = fmaxf(vy, 0.f); }
  Out[(size_t)pass * N * CPU + (size_t)n * CPU + cp] = pack_bf16x2(vx, vy);
}

// ---------------- decode: logits[i] = dot(z[a[i]], z[b[i]]) ----------------
// z stored pass-major [2][N][16 uints]; 8 lanes per pair: lanes 0-3 read
// pass 0 (uint4 each), lanes 4-7 read pass 1. Direct store, no atomics.

__global__ __launch_bounds__(256) void k_decode(const unsigned* __restrict__ Z,
                                                const int* __restrict__ ia,
                                                const int* __restrict__ ib,
                                                float* __restrict__ out, int N, int L) {
  int t = blockIdx.x * 256 + threadIdx.x;
  int i = t >> 3;
  if (i >= L) return;
  int e = t & 7;
  int a = ia[i], b = ib[i];
  size_t base = (size_t)(e >> 2) * N * 16 + (size_t)(e & 3) * 4;
  uint4 za = *(const uint4*)&Z[base + (size_t)a * 16];
  uint4 zb = *(const uint4*)&Z[base + (size_t)b * 16];
  float p = bf_lo(za.x) * bf_lo(zb.x) + bf_hi(za.x) * bf_hi(zb.x)
          + bf_lo(za.y) * bf_lo(zb.y) + bf_hi(za.y) * bf_hi(zb.y)
          + bf_lo(za.z) * bf_lo(zb.z) + bf_hi(za.z) * bf_hi(zb.z)
          + bf_lo(za.w) * bf_lo(zb.w) + bf_hi(za.w) * bf_hi(zb.w);
  p += __shfl_xor(p, 1);
  p += __shfl_xor(p, 2);
  p += __shfl_xor(p, 4);
  if (e == 0) out[i] = p;
}

extern "C" void kernel_launch(void* const* d_in, const int* in_sizes, int n_in,
                              void* d_out, int out_size, void* d_ws, size_t ws_size,
                              hipStream_t stream) {
  const float* x   = (const float*)d_in[0];
  const int*   ei  = (const int*)d_in[1];
  const int*   eli = (const int*)d_in[2];
  const float* W1  = (const float*)d_in[3];
  const float* b1  = (const float*)d_in[4];
  const float* W2  = (const float*)d_in[5];
  const float* b2  = (const float*)d_in[6];
  float* logits = (float*)d_out;

  int N = in_sizes[0] / IN_CH;
  int E = in_sizes[1] / 2;
  int L = in_sizes[2] / 2;
  const int* src = ei;
  const int* dst = ei + E;
  const int* la  = eli;
  const int* lb  = eli + L;

  char* ws = (char*)d_ws;
  size_t off = 0;
  auto alloc = [&](size_t bytes) {
    void* p = ws + off;
    off = (off + bytes + 255) & ~(size_t)255;
    return p;
  };
  int*      cnt    = (int*)alloc((size_t)N * 4);
  int*      rowptr = (int*)alloc((size_t)(N + 1) * 4);
  float*    dinv   = (float*)alloc((size_t)N * 4);
  int*      col    = (int*)alloc((size_t)E * 4);
  int*      ord    = (int*)alloc((size_t)E * 4);
  unsigned short* hsp  = (unsigned short*)alloc((size_t)N * HID_CH * 2);  // [2][N][64] bf16
  unsigned short* hrbp = (unsigned short*)alloc((size_t)N * HID_CH * 2);  // [2][N][64] bf16
  unsigned short* h2sp = (unsigned short*)alloc((size_t)N * OUT_CH * 2);  // [2][N][32] bf16
  unsigned short* zup  = (unsigned short*)alloc((size_t)N * OUT_CH * 2);  // [2][N][32] bf16
  int*      bsum   = (int*)alloc(256 * 4);

  const int TB = 256;
  int nscan = (N + SCAN_CHUNK - 1) / SCAN_CHUNK;
  // cnt must be zero EVERY call (harness doesn't re-poison between replays)
  k_zero<<<(N / 4 + TB - 1) / TB, TB, 0, stream>>>(cnt, N);
  k_count<<<(E / 4 + TB - 1) / TB, TB, 0, stream>>>(dst, cnt, ord, E);
  k_scan_part<<<nscan, 256, 0, stream>>>(cnt, bsum, dinv, N);
  k_scan_fill<<<nscan, 256, 0, stream>>>(cnt, bsum, rowptr, N, E);
  k_fill <<<(E / 4 + TB - 1) / TB, TB, 0, stream>>>(src, dst, ord, rowptr, col, E);

  // layer 1: hsp = bf16((x@W1)*dinv) [2][N][64] ; hrbp = relu-agg, same layout
  k_gemm<HID_CH, false><<<(N + 63) / 64, 256, 0, stream>>>(x, W1, dinv, hsp, N);
  {
    int nchunk = (N + 8 * 4 - 1) / (8 * 4);     // NPB=8 nodes/block, 4 subs
    k_agg<32, true><<<nchunk * 8, 256, 0, stream>>>(
        (const unsigned*)hsp, rowptr, col, dinv, b1, (unsigned*)hrbp, N);
  }

  // layer 2: h2sp = bf16((hrbp@W2)*dinv) [2][N][32] ; zup = agg, same layout
  k_gemm<OUT_CH, true><<<(N + 63) / 64, 256, 0, stream>>>(hrbp, W2, dinv, h2sp, N);
  {
    int nchunk = (N + 16 * 4 - 1) / (16 * 4);   // NPB=16 nodes/block, 4 subs
    k_agg<16, false><<<nchunk * 8, 256, 0, stream>>>(
        (const unsigned*)h2sp, rowptr, col, dinv, b2, (unsigned*)zup, N);
  }

  // decode
  k_decode<<<((size_t)L * 8 + 255) / 256, 256, 0, stream>>>(
      (const unsigned*)zup, la, lb, logits, N, L);
}